// Round 9
// baseline (248.185 us; speedup 1.0000x reference)
//
#include <hip/hip_runtime.h>
#include <hip/hip_fp16.h>
#include <math.h>

#define WAVE   64
#define NPB    16          // nodes per (single-wave) block
#define BLOCKT 64          // one wave per block: no cross-wave barriers
#define SMAX   3           // stashed 256-edge chunks (covers <=768 edges/window; avg 512)

// ---- constants from the reference ----
#define KC        2.2281692032865347f   // 7/pi
#define H         0.05f
#define INV_H2    400.0f
#define INV_H3    8000.0f
#define EPS_REF   0.00025f              // h^2 * 0.1
#define K_OUT     0.24261080f           // 2*h*DELTA*C0
#define REST_RHO  1000.0f

__device__ __forceinline__ float wendland_dkdq(float q) {
    float o = 1.f - q;
    return -20.f * q * o * o * o * KC;
}

union H2F { __half2 h; float f; };
__device__ __forceinline__ float   h2_as_f(__half2 h) { H2F u; u.h = h; return u.f; }
__device__ __forceinline__ __half2 f_as_h2(float f)   { H2F u; u.f = f; return u.h; }

// largest li in [0,NPB) with rp[li] <= e   (rp[0] <= e < rp[NPB] guaranteed)
__device__ __forceinline__ int li_search(const int* rp, int e) {
    int lo = 0;
#pragma unroll
    for (int s = NPB / 2; s >= 1; s >>= 1) lo += (rp[lo + s] <= e) ? s : 0;
    return lo;
}

// ---------------------------------------------------------------------------
// 4-edge-per-lane segmented reduction (proven R2/R5/R6/R7). Equal keys
// contiguous in lane order; key<0 skipped. base is LDS here.
// ---------------------------------------------------------------------------
template<int NV>
__device__ __forceinline__ void seg_reduce4(const int k[4], float v[4][NV], float* base) {
    const int lane = threadIdx.x & (WAVE - 1);
    const int k0 = k[0], k3 = k[3];
    const bool split = (k0 != k3);
    const int firstLen  = (k[1]==k0) ? ((k[2]==k0) ? ((k[3]==k0)?4:3) : 2) : 1;
    const int lastStart = (k[2]==k3) ? ((k[1]==k3) ? ((k[0]==k3)?0:1) : 2) : 3;

    float vin[NV], vfirst[NV];
#pragma unroll
    for (int c = 0; c < NV; ++c) {
        float s = v[3][c];
        if (lastStart <= 2) s += v[2][c];
        if (lastStart <= 1) s += v[1][c];
        if (lastStart == 0) s += v[0][c];
        vin[c] = s;
        float f = v[0][c];
        if (firstLen >= 2) f += v[1][c];
        if (firstLen >= 3) f += v[2][c];
        if (firstLen >= 4) f += v[3][c];
        vfirst[c] = f;
    }
#pragma unroll
    for (int idx = 1; idx <= 2; ++idx) {
        if (idx >= firstLen && idx < lastStart && k[idx] >= 0) {
#pragma unroll
            for (int c = 0; c < NV; ++c)
                atomicAdd(base + (size_t)k[idx] * NV + c, v[idx][c]);
        }
    }
    float S[NV];
#pragma unroll
    for (int c = 0; c < NV; ++c) S[c] = vin[c];
    const int klast = k3;
#pragma unroll
    for (int d = 1; d < WAVE; d <<= 1) {
        int okey = __shfl_up(klast, d, WAVE);
        float ov[NV];
#pragma unroll
        for (int c = 0; c < NV; ++c) ov[c] = __shfl_up(S[c], d, WAVE);
        if (lane >= d && okey == klast) {
#pragma unroll
            for (int c = 0; c < NV; ++c) S[c] += ov[c];
        }
    }
    const int prevk = __shfl_up(klast, 1, WAVE);
    float P[NV];
#pragma unroll
    for (int c = 0; c < NV; ++c) P[c] = __shfl_up(S[c], 1, WAVE);
    if (split && k0 >= 0) {
        const bool carry = (lane > 0 && prevk == k0);
#pragma unroll
        for (int c = 0; c < NV; ++c)
            atomicAdd(base + (size_t)k0 * NV + c, vfirst[c] + (carry ? P[c] : 0.f));
    }
    const int nk0 = __shfl_down(k0, 1, WAVE);
    const bool tail = (lane == WAVE - 1) || (nk0 != klast);
    if (tail && klast >= 0) {
#pragma unroll
        for (int c = 0; c < NV; ++c)
            atomicAdd(base + (size_t)klast * NV + c, S[c]);
    }
}

struct EW { int jv[4]; float qv[4], dxv[4], dyv[4]; bool okv[4]; };

__device__ __forceinline__ void load_win(long e0, int beg, int end, int E,
        const int* __restrict__ ej, const float* __restrict__ qarr,
        const float2* __restrict__ dirs, EW& w) {
    if (e0 + 3 < (long)E) {
        int4   j4 = *(const int4*)(ej + e0);
        float4 q4 = *(const float4*)(qarr + e0);
        float4 dA = *(const float4*)((const float*)dirs + 2 * e0);
        float4 dB = *(const float4*)((const float*)dirs + 2 * e0 + 4);
        w.jv[0]=j4.x; w.jv[1]=j4.y; w.jv[2]=j4.z; w.jv[3]=j4.w;
        w.qv[0]=q4.x; w.qv[1]=q4.y; w.qv[2]=q4.z; w.qv[3]=q4.w;
        w.dxv[0]=dA.x; w.dyv[0]=dA.y; w.dxv[1]=dA.z; w.dyv[1]=dA.w;
        w.dxv[2]=dB.x; w.dyv[2]=dB.y; w.dxv[3]=dB.z; w.dyv[3]=dB.w;
    } else {
#pragma unroll
        for (int u = 0; u < 4; ++u) {
            long e = e0 + u;
            if (e < (long)E) {
                w.jv[u] = ej[e]; w.qv[u] = qarr[e];
                float2 d = dirs[e]; w.dxv[u] = d.x; w.dyv[u] = d.y;
            } else { w.jv[u]=0; w.qv[u]=0.f; w.dxv[u]=0.f; w.dyv[u]=0.f; }
        }
    }
#pragma unroll
    for (int u = 0; u < 4; ++u) {
        long e = e0 + u;
        w.okv[u] = (e >= (long)beg) && (e < (long)end);
    }
}

// rowptr[t] = first edge e with i[e] >= t (i sorted); also pack vd=(vol,dens).
__global__ void k_prep(const int* __restrict__ ei, const float* __restrict__ vol,
                       const float* __restrict__ dens, int* __restrict__ rowptr,
                       float2* __restrict__ vd, int N, int E) {
    int e = blockIdx.x * blockDim.x + threadIdx.x;
    if (e <= E) {
        int prev = (e == 0) ? -1 : ei[e - 1];
        int cur  = (e == E) ? N  : ei[e];
        for (int t = prev + 1; t <= cur; ++t) rowptr[t] = e;
    }
    if (e < N) vd[e] = make_float2(vol[e], dens[e]);
}

// Fused A+B+C+terms1/2 — ONE WAVE per block, 16 nodes, ~512 edges.
__global__ __launch_bounds__(BLOCKT)
void k_AC(const int* __restrict__ ej, const float* __restrict__ qarr,
          const float2* __restrict__ dirs, const float2* __restrict__ vd,
          const int* __restrict__ rowptr, __half2* __restrict__ cst,
          float2* __restrict__ g2, float* __restrict__ outp, int N, int E) {
    __shared__ int    rp[NPB + 1];
    __shared__ float  acc6[NPB * 6];     // m00,m01,m11,A,Bx,By
    __shared__ float  Lild[NPB * 3];
    __shared__ float  gld[NPB * 2];
    __shared__ float2 vdl[NPB];
    const int tid = threadIdx.x;
    const int n0  = blockIdx.x * NPB;
    const int nHi = min(n0 + NPB, N);
    if (tid <= NPB) rp[tid] = rowptr[min(n0 + tid, nHi)];
    if (tid < NPB && n0 + tid < N) vdl[tid] = vd[n0 + tid];
    // BUGFIX (R8): NPB*6 = 96 > 64 threads — must stride, not mask.
    for (int x = tid; x < NPB * 6; x += BLOCKT) acc6[x] = 0.f;
    if (tid < NPB * 2) gld[tid] = 0.f;
    __syncthreads();                      // 1-wave block: compiles to waitcnt
    const int  beg = rp[0], end = rp[NPB];
    const long beg4 = (long)beg & ~3L;

    // stash: (gwx,gwy,val,li) per edge, up to 12 edges/lane
    int   li_s[4 * SMAX];
    float gwx_s[4 * SMAX], gwy_s[4 * SMAX], val_s[4 * SMAX];
#pragma unroll
    for (int x = 0; x < 4 * SMAX; ++x) { li_s[x] = -1; gwx_s[x]=gwy_s[x]=val_s[x]=0.f; }

    // ---- phase A: M + A + B, stream cst ----
#pragma unroll
    for (int c = 0; c < SMAX; ++c) {
        long ebw = beg4 + (long)c * BLOCKT * 4;
        if (ebw < (long)end) {
            long e0 = beg4 + ((long)c * BLOCKT + tid) * 4;
            EW wd; load_win(e0, beg, end, E, ej, qarr, dirs, wd);
            const bool all4 = wd.okv[0] && wd.okv[1] && wd.okv[2] && wd.okv[3];
            float4 cpack;
            int k[4]; float v[4][6];
#pragma unroll
            for (int u = 0; u < 4; ++u) {
                k[u] = -1;
#pragma unroll
                for (int c2 = 0; c2 < 6; ++c2) v[u][c2] = 0.f;
                if (wd.okv[u]) {
                    int li = li_search(rp, (int)(e0 + u));
                    float q = wd.qv[u], dx = wd.dxv[u], dy = wd.dyv[u];
                    float2 vdj = vd[wd.jv[u]];
                    float wq = wendland_dkdq(q);
                    float s = -2.f * vdj.x * q * wq * INV_H2;   // >= 0
                    float w = wq * INV_H3;
                    float gwx = dx * w, gwy = dy * w;
                    float rx = -dx * q * H, ry = -dy * q * H;
                    float rji2 = rx * rx + ry * ry + EPS_REF;
                    float gT = (gwx * rx + gwy * ry) / rji2;
                    float gv = gT * vdj.x;
                    float rho_ba = REST_RHO * (vdj.y - vdl[li].y);
                    k[u] = li;
                    v[u][0] = s * dx * dx; v[u][1] = s * dx * dy; v[u][2] = s * dy * dy;
                    v[u][3] = rho_ba * gv; v[u][4] = rx * gv;    v[u][5] = ry * gv;
                    __half2 cp = __floats2half2_rn(0.5f * rx * gv, 0.5f * ry * gv);
                    if (all4) (&cpack.x)[u] = h2_as_f(cp);
                    else      cst[e0 + u] = cp;
                    li_s[c*4+u] = li; gwx_s[c*4+u] = gwx; gwy_s[c*4+u] = gwy;
                    val_s[c*4+u] = 2.f * rho_ba * vdj.x;
                }
            }
            if (all4) ((float4*)cst)[e0 >> 2] = cpack;
            seg_reduce4<6>(k, v, acc6);
        }
    }
    for (int c = SMAX; ; ++c) {   // overflow (window > 768 edges; ~never)
        long ebw = beg4 + (long)c * BLOCKT * 4;
        if (ebw >= (long)end) break;
        long e0 = beg4 + ((long)c * BLOCKT + tid) * 4;
        EW wd; load_win(e0, beg, end, E, ej, qarr, dirs, wd);
        int k[4]; float v[4][6];
#pragma unroll
        for (int u = 0; u < 4; ++u) {
            k[u] = -1;
#pragma unroll
            for (int c2 = 0; c2 < 6; ++c2) v[u][c2] = 0.f;
            if (wd.okv[u]) {
                int li = li_search(rp, (int)(e0 + u));
                float q = wd.qv[u], dx = wd.dxv[u], dy = wd.dyv[u];
                float2 vdj = vd[wd.jv[u]];
                float wq = wendland_dkdq(q);
                float s = -2.f * vdj.x * q * wq * INV_H2;
                float w = wq * INV_H3;
                float gwx = dx * w, gwy = dy * w;
                float rx = -dx * q * H, ry = -dy * q * H;
                float rji2 = rx * rx + ry * ry + EPS_REF;
                float gT = (gwx * rx + gwy * ry) / rji2;
                float gv = gT * vdj.x;
                float rho_ba = REST_RHO * (vdj.y - vdl[li].y);
                k[u] = li;
                v[u][0] = s * dx * dx; v[u][1] = s * dx * dy; v[u][2] = s * dy * dy;
                v[u][3] = rho_ba * gv; v[u][4] = rx * gv;    v[u][5] = ry * gv;
                cst[e0 + u] = __floats2half2_rn(0.5f * rx * gv, 0.5f * ry * gv);
            }
        }
        seg_reduce4<6>(k, v, acc6);
    }
    __syncthreads();

    // ---- pinv (JAX cutoff semantics), one lane per node ----
    if (tid < NPB) {
        float a = acc6[6*tid], b = acc6[6*tid+1], cc = acc6[6*tid+2];
        float half_tr   = 0.5f * (a + cc);
        float half_diff = 0.5f * (a - cc);
        float disc = sqrtf(half_diff * half_diff + b * b);
        float l1 = half_tr + disc, l2 = half_tr - disc;
        float smax = fmaxf(fabsf(l1), fabsf(l2));
        float cutoff = 2.3841858e-6f * smax;   // rcond = 10*max(2,2)*eps_f32
        float i00 = 0.f, i01 = 0.f, i11 = 0.f;
        if (fabsf(l2) > cutoff) {
            float inv = 1.0f / (a * cc - b * b);
            i00 =  cc * inv; i01 = -b * inv; i11 = a * inv;
        } else if (fabsf(l1) > cutoff) {
            float vax = b,       vay = l1 - a;
            float vbx = l1 - cc, vby = b;
            float na = vax*vax + vay*vay, nb = vbx*vbx + vby*vby;
            float vx, vy, n2;
            if (nb >= na) { vx = vbx; vy = vby; n2 = nb; }
            else          { vx = vax; vy = vay; n2 = na; }
            float inv = 1.0f / (l1 * n2);
            i00 = vx*vx*inv; i01 = vx*vy*inv; i11 = vy*vy*inv;
        }
        Lild[3*tid] = i00; Lild[3*tid+1] = i01; Lild[3*tid+2] = i11;
    }
    __syncthreads();

    // ---- phase C: gradRho from stash ----
#pragma unroll
    for (int c = 0; c < SMAX; ++c) {
        long ebw = beg4 + (long)c * BLOCKT * 4;
        if (ebw < (long)end) {
            int k[4]; float v[4][2];
#pragma unroll
            for (int u = 0; u < 4; ++u) {
                int li = li_s[c*4+u];
                k[u] = li; v[u][0] = v[u][1] = 0.f;
                if (li >= 0) {
                    float gwx = gwx_s[c*4+u], gwy = gwy_s[c*4+u];
                    float L0 = Lild[3*li], L1 = Lild[3*li+1], L2v = Lild[3*li+2];
                    float gx = L0 * gwx + L1 * gwy;
                    float gy = L1 * gwx + L2v * gwy;
                    float dm = fabsf(gwx) + fabsf(gwy);
                    float nm = fabsf(gx) + fabsf(gy);
                    float change = fabsf(nm - dm) / (dm + 1e-4f * H);
                    if (!(change < 0.1f)) { gx = gwx; gy = gwy; }   // NaN -> fallback
                    v[u][0] = val_s[c*4+u] * gx;
                    v[u][1] = val_s[c*4+u] * gy;
                }
            }
            seg_reduce4<2>(k, v, gld);
        }
    }
    for (int c = SMAX; ; ++c) {   // overflow recompute (rare)
        long ebw = beg4 + (long)c * BLOCKT * 4;
        if (ebw >= (long)end) break;
        long e0 = beg4 + ((long)c * BLOCKT + tid) * 4;
        EW wd; load_win(e0, beg, end, E, ej, qarr, dirs, wd);
        int k[4]; float v[4][2];
#pragma unroll
        for (int u = 0; u < 4; ++u) {
            k[u] = -1; v[u][0] = v[u][1] = 0.f;
            if (wd.okv[u]) {
                int li = li_search(rp, (int)(e0 + u));
                float q = wd.qv[u], dx = wd.dxv[u], dy = wd.dyv[u];
                float2 vdj = vd[wd.jv[u]];
                float w = wendland_dkdq(q) * INV_H3;
                float gwx = dx * w, gwy = dy * w;
                float L0 = Lild[3*li], L1 = Lild[3*li+1], L2v = Lild[3*li+2];
                float gx = L0 * gwx + L1 * gwy;
                float gy = L1 * gwx + L2v * gwy;
                float dm = fabsf(gwx) + fabsf(gwy);
                float nm = fabsf(gx) + fabsf(gy);
                float change = fabsf(nm - dm) / (dm + 1e-4f * H);
                if (!(change < 0.1f)) { gx = gwx; gy = gwy; }
                float val = 2.f * REST_RHO * (vdj.y - vdl[li].y) * vdj.x;
                k[u] = li; v[u][0] = val * gx; v[u][1] = val * gy;
            }
        }
        seg_reduce4<2>(k, v, gld);
    }
    __syncthreads();
    if (tid < NPB && n0 + tid < N) {
        float gx = gld[2*tid], gy = gld[2*tid+1];
        g2[n0 + tid]   = make_float2(gx, gy);
        outp[n0 + tid] = acc6[6*tid+3] + 0.5f * (gx * acc6[6*tid+4] + gy * acc6[6*tid+5]);
    }
}

// Pass D (term 3): out = K_OUT * (outp + sum_e <g[j], c_e>). One wave per block.
__global__ __launch_bounds__(BLOCKT)
void k_D(const int* __restrict__ ej, const __half2* __restrict__ cst,
         const float2* __restrict__ g2, const float* __restrict__ outp,
         const int* __restrict__ rowptr, float* __restrict__ out, int N, int E) {
    __shared__ int   rp[NPB + 1];
    __shared__ float outl[NPB];
    const int tid = threadIdx.x;
    const int n0  = blockIdx.x * NPB;
    const int nHi = min(n0 + NPB, N);
    if (tid <= NPB) rp[tid] = rowptr[min(n0 + tid, nHi)];
    if (tid < NPB) outl[tid] = 0.f;
    __syncthreads();
    const int  beg = rp[0], end = rp[NPB];
    const long beg4 = (long)beg & ~3L;

    for (int c = 0; ; ++c) {
        long ebw = beg4 + (long)c * BLOCKT * 4;
        if (ebw >= (long)end) break;
        long e0 = beg4 + ((long)c * BLOCKT + tid) * 4;
        int jv[4]; float cv[4];
        if (e0 + 3 < (long)E) {
            int4   j4 = *(const int4*)(ej + e0);
            float4 c4 = ((const float4*)cst)[e0 >> 2];
            jv[0]=j4.x; jv[1]=j4.y; jv[2]=j4.z; jv[3]=j4.w;
            cv[0]=c4.x; cv[1]=c4.y; cv[2]=c4.z; cv[3]=c4.w;
        } else {
#pragma unroll
            for (int u = 0; u < 4; ++u) {
                long e = e0 + u;
                if (e < (long)E) { jv[u] = ej[e]; cv[u] = h2_as_f(cst[e]); }
                else             { jv[u] = 0;     cv[u] = 0.f; }
            }
        }
        int k[4]; float v[4][1];
#pragma unroll
        for (int u = 0; u < 4; ++u) {
            long e = e0 + u;
            k[u] = -1; v[u][0] = 0.f;
            if (e >= (long)beg && e < (long)end) {
                int li = li_search(rp, (int)e);
                float2 gj = g2[jv[u]];                 // L2-resident gather
                __half2 ch = f_as_h2(cv[u]);
                k[u] = li;
                v[u][0] = gj.x * __low2float(ch) + gj.y * __high2float(ch);
            }
        }
        seg_reduce4<1>(k, v, outl);
    }
    __syncthreads();
    if (tid < NPB && n0 + tid < N)
        out[n0 + tid] = K_OUT * (outp[n0 + tid] + outl[tid]);
}

extern "C" void kernel_launch(void* const* d_in, const int* in_sizes, int n_in,
                              void* d_out, int out_size, void* d_ws, size_t ws_size,
                              hipStream_t stream) {
    const float*  vol  = (const float*)d_in[1];
    const float*  dens = (const float*)d_in[2];
    const float2* dirs = (const float2*)d_in[3];
    const float*  qarr = (const float*)d_in[4];
    const int*    ei   = (const int*)d_in[5];
    const int*    ej   = (const int*)d_in[6];
    const int N = in_sizes[1];
    const int E = in_sizes[4];

    // ws: rowptr int[N+1] | vd f2[N] | g2 f2[N] | outp f[N] | cst h2[E]  (~30.5 MB)
    size_t off = 0;
    auto alloc = [&](size_t bytes) { void* r = (char*)d_ws + off;
                                     off = (off + bytes + 15) & ~(size_t)15; return r; };
    int*     rowptr = (int*)    alloc((size_t)(N + 1) * 4);
    float2*  vd     = (float2*) alloc((size_t)N * 8);
    float2*  g2     = (float2*) alloc((size_t)N * 8);
    float*   outp   = (float*)  alloc((size_t)N * 4);
    __half2* cst    = (__half2*)alloc((size_t)E * 4);
    float*   out    = (float*)d_out;

    const int tb = 256;
    const int gP = (E + 1 + tb - 1) / tb;
    const int gB = (N + NPB - 1) / NPB;     // 12500 single-wave blocks

    k_prep<<<gP, tb, 0, stream>>>(ei, vol, dens, rowptr, vd, N, E);
    k_AC  <<<gB, BLOCKT, 0, stream>>>(ej, qarr, dirs, vd, rowptr, cst, g2, outp, N, E);
    k_D   <<<gB, BLOCKT, 0, stream>>>(ej, cst, g2, outp, rowptr, out, N, E);
}